// Round 3
// baseline (378.211 us; speedup 1.0000x reference)
//
#include <hip/hip_runtime.h>
#include <hip/hip_bf16.h>
#include <hip/hip_cooperative_groups.h>

namespace cg = cooperative_groups;

typedef unsigned short u16;
typedef short short8_t __attribute__((ext_vector_type(8)));
typedef float floatx4 __attribute__((ext_vector_type(4)));

constexpr int NT = 4096, H = 128, CAP = 64;
constexpr int GRID = 256, BLK = 512, GSTRIDE = GRID * BLK;

// bf16 weight arena element offsets (lat1+b1 contiguous -> one 192-col head GEMM)
constexpr int OFF_QKV  = 0;                 // 4*384*128
constexpr int OFF_AO   = 196608;            // 4*128*128
constexpr int OFF_F1   = 262144;            // 4*256*128
constexpr int OFF_F2   = 393216;            // 4*128*256
constexpr int OFF_LAT1 = 524288;            // 128*128
constexpr int OFF_B1   = 540672;            // 64*128
constexpr int OFF_LAT2 = 548864;            // 16*128
constexpr int W_TOTAL  = 550912;

__device__ __forceinline__ float bfu(u16 u) { return __uint_as_float(((unsigned)u) << 16); }
__device__ __forceinline__ u16 f2bf(float f) {
  unsigned u = __float_as_uint(f);
  u += 0x7fffu + ((u >> 16) & 1u);          // RNE
  return (u16)(u >> 16);
}
__device__ __forceinline__ void unpack8(uint4 u, float* f) {
  f[0] = __uint_as_float(u.x << 16); f[1] = __uint_as_float(u.x & 0xffff0000u);
  f[2] = __uint_as_float(u.y << 16); f[3] = __uint_as_float(u.y & 0xffff0000u);
  f[4] = __uint_as_float(u.z << 16); f[5] = __uint_as_float(u.z & 0xffff0000u);
  f[6] = __uint_as_float(u.w << 16); f[7] = __uint_as_float(u.w & 0xffff0000u);
}

struct Prm {
  const float *xr, *in_w, *in_b, *ln1_s, *ln1_b, *qkv_w, *qkv_b, *ao_w, *ao_b,
              *ln2_s, *ln2_b, *f1_w, *f1_b, *f2_w, *f2_b, *lat1_w, *lat1_b,
              *lat2_w, *lat2_b, *b1_w, *b1_b, *b2_w, *b2_b;
  u16* W; float* X; u16* QKV; int* NI; int* NC; double* EP; float* out;
};

// One persistent cooperative kernel: block b owns token rows [16b, 16b+16)
// for the whole network; only prep->all and qkv->attn need grid-wide syncs.
__global__ __launch_bounds__(BLK, 2) void mega_kernel(Prm p) {
  const int t = threadIdx.x, bid = blockIdx.x;
  const int lane = t & 63, w = t >> 6;          // 8 waves
  const int lr = lane & 15, quad = lane >> 4;
  const int gtid = bid * BLK + t;
  const int r0 = bid * 16;                      // this block's 16 token rows
  cg::grid_group grid = cg::this_grid();
  const floatx4 FZ = {0.f, 0.f, 0.f, 0.f};

  __shared__ union {
    unsigned long long words[8][64];                     // 4 KB (nbr stage)
    struct { u16 A16[16][136]; u16 FF1[16][264]; } g;    // 4.35 + 8.45 KB
  } sm;

  // stage X rows -> bf16 A-tile in LDS, optional fused LayerNorm.
  // 512 thr: row = t>>5 (32 lanes/row), 4 cols each; +8 pad kills LDS conflicts.
  auto stage_x = [&](const float* sc, const float* bi, bool do_ln) {
    const int r = t >> 5, j0 = (t & 31) * 4;
    const float4 xv = *(const float4*)&p.X[(size_t)(r0 + r) * H + j0];
    float v0 = xv.x, v1 = xv.y, v2 = xv.z, v3 = xv.w;
    if (do_ln) {
      float s = v0 + v1 + v2 + v3;
      float ss = v0 * v0 + v1 * v1 + v2 * v2 + v3 * v3;
#pragma unroll
      for (int off = 1; off <= 16; off <<= 1) {
        s += __shfl_xor(s, off); ss += __shfl_xor(ss, off);
      }
      const float mean = s * (1.f / 128.f);
      const float rstd = rsqrtf(ss * (1.f / 128.f) - mean * mean + 1e-5f);
      v0 = (v0 - mean) * rstd * sc[j0]     + bi[j0];
      v1 = (v1 - mean) * rstd * sc[j0 + 1] + bi[j0 + 1];
      v2 = (v2 - mean) * rstd * sc[j0 + 2] + bi[j0 + 2];
      v3 = (v3 - mean) * rstd * sc[j0 + 3] + bi[j0 + 3];
    }
    uint2 pk;
    pk.x = (unsigned)f2bf(v0) | ((unsigned)f2bf(v1) << 16);
    pk.y = (unsigned)f2bf(v2) | ((unsigned)f2bf(v3) << 16);
    *(uint2*)&sm.g.A16[r][j0] = pk;
  };

  // qkv GEMM for this block's 16 rows, N=384, K=128; A in sm.g.A16.
  auto qkv_phase = [&](int lw) {
    const u16* Bw = p.W + OFF_QKV + lw * 49152;
    const float* qb = p.qkv_b + lw * 384;
    const int c0 = w * 48;
    floatx4 a0 = FZ, a1 = FZ, a2 = FZ;
#pragma unroll
    for (int k0 = 0; k0 < 128; k0 += 32) {
      short8_t a  = *(const short8_t*)&sm.g.A16[lr][k0 + quad * 8];
      short8_t b0 = *(const short8_t*)&Bw[(size_t)(c0 + lr) * 128 + k0 + quad * 8];
      short8_t b1 = *(const short8_t*)&Bw[(size_t)(c0 + 16 + lr) * 128 + k0 + quad * 8];
      short8_t b2 = *(const short8_t*)&Bw[(size_t)(c0 + 32 + lr) * 128 + k0 + quad * 8];
      a0 = __builtin_amdgcn_mfma_f32_16x16x32_bf16(a, b0, a0, 0, 0, 0);
      a1 = __builtin_amdgcn_mfma_f32_16x16x32_bf16(a, b1, a1, 0, 0, 0);
      a2 = __builtin_amdgcn_mfma_f32_16x16x32_bf16(a, b2, a2, 0, 0, 0);
    }
#pragma unroll
    for (int r = 0; r < 4; ++r) {
      const size_t row = (size_t)(r0 + quad * 4 + r) * 384;
      p.QKV[row + c0 + lr]      = f2bf(a0[r] + qb[c0 + lr]);
      p.QKV[row + c0 + 16 + lr] = f2bf(a1[r] + qb[c0 + 16 + lr]);
      p.QKV[row + c0 + 32 + lr] = f2bf(a2[r] + qb[c0 + 32 + lr]);
    }
  };

  // ================= stage P: wconv + eta/phi + in_proj =================
  for (int i = gtid; i < W_TOTAL; i += GSTRIDE) {
    float v;
    if      (i < OFF_AO)   v = p.qkv_w[i];
    else if (i < OFF_F1)   v = p.ao_w[i - OFF_AO];
    else if (i < OFF_F2)   v = p.f1_w[i - OFF_F1];
    else if (i < OFF_LAT1) v = p.f2_w[i - OFF_F2];
    else if (i < OFF_B1)   v = p.lat1_w[i - OFF_LAT1];
    else if (i < OFF_LAT2) v = p.b1_w[i - OFF_B1];
    else                   v = p.lat2_w[i - OFF_LAT2];
    p.W[i] = f2bf(v);
  }
  if (gtid < NT) {
    p.EP[gtid * 2]     = (double)p.xr[gtid * 16 + 1] * 5.24 - 2.62;
    p.EP[gtid * 2 + 1] = (double)p.xr[gtid * 16 + 2] * 6.2832 - 3.1416;
  }
  for (int i = gtid; i < NT * H; i += GSTRIDE) {
    const int r = i >> 7, c = i & 127;
    const float* xp = p.xr + r * 16;
    const float* wp = p.in_w + c * 16;
    float acc = p.in_b[c];
#pragma unroll
    for (int k = 0; k < 16; ++k) acc += xp[k] * wp[k];
    p.X[i] = acc;
  }
  grid.sync();

  // ================= stage N: neighbor lists + qkv layer 0 =================
  for (int u = bid; u < NT / 8; u += GRID) {
    const int q0 = u * 8;
    double qe[8], qp_[8];
#pragma unroll
    for (int j = 0; j < 8; ++j) { qe[j] = p.EP[(q0 + j) * 2]; qp_[j] = p.EP[(q0 + j) * 2 + 1]; }
    for (int c = 0; c < 8; ++c) {
      const int k = c * 512 + t;
      const double ke = p.EP[k * 2], kp = p.EP[k * 2 + 1];
#pragma unroll
      for (int j = 0; j < 8; ++j) {
        const double de = qe[j] - ke;
        double dp = qp_[j] - kp;
        dp -= 6.283185307179586 * rint(dp * 0.15915494309189535);  // == atan2 wrap
        const unsigned long long bm = __ballot((de * de + dp * dp) <= 0.04);
        if (lane == 0) sm.words[j][c * 8 + w] = bm;
      }
    }
    __syncthreads();
    {
      unsigned long long m = sm.words[w][lane];
      const int cnt = __popcll(m);
      int incl = cnt;
#pragma unroll
      for (int off = 1; off < 64; off <<= 1) {
        const int n = __shfl_up(incl, off);
        if (lane >= off) incl += n;
      }
      int pos = incl - cnt;
      const int qq = q0 + w;
      const int kbase = (lane >> 3) * 512 + (lane & 7) * 64;
      while (m) {
        const int b = __builtin_ctzll(m);
        m &= m - 1;
        if (pos < CAP) p.NI[qq * CAP + pos] = kbase + b;
        ++pos;
      }
      if (lane == 63) p.NC[qq] = incl > CAP ? CAP : incl;
    }
    __syncthreads();
  }
  stage_x(p.ln1_s, p.ln1_b, true);
  __syncthreads();
  qkv_phase(0);
  grid.sync();

  // ================= layer stages =================
  for (int l = 0; l < 4; ++l) {
    // --- attention: 128 (q,h) pairs, 4 threads/pair split over neighbors ---
    {
      const int pr = t >> 2, sub = t & 3;
      const int q = r0 + (pr >> 3), h = pr & 7;
      const u16* qp = p.QKV + (size_t)q * 384 + h * 16;
      float qv[16];
      { uint4 a = *(const uint4*)qp, b = *(const uint4*)(qp + 8);
        unpack8(a, qv); unpack8(b, qv + 8); }
#pragma unroll
      for (int d = 0; d < 16; ++d) qv[d] *= 0.25f;      // 1/sqrt(HD)
      float o[16];
#pragma unroll
      for (int d = 0; d < 16; ++d) o[d] = 0.f;
      float se = 0.f;
      const int cnt = p.NC[q];
      const int* nl = p.NI + q * CAP;
      for (int i = sub; i < cnt; i += 4) {
        const int nb = nl[i];
        const u16* kp = p.QKV + (size_t)nb * 384 + 128 + h * 16;
        float kv[16], vv[16];
        { uint4 a = *(const uint4*)kp;         uint4 b = *(const uint4*)(kp + 8);
          unpack8(a, kv); unpack8(b, kv + 8); }
        { uint4 a = *(const uint4*)(kp + 128); uint4 b = *(const uint4*)(kp + 136);
          unpack8(a, vv); unpack8(b, vv + 8); }
        float s0 = 0.f, s1 = 0.f, s2 = 0.f, s3 = 0.f;
#pragma unroll
        for (int d = 0; d < 16; d += 4) {
          s0 += qv[d] * kv[d];       s1 += qv[d + 1] * kv[d + 1];
          s2 += qv[d + 2] * kv[d + 2]; s3 += qv[d + 3] * kv[d + 3];
        }
        const float e = expf((s0 + s1) + (s2 + s3));    // |s|<~0.5, no max-sub
        se += e;
#pragma unroll
        for (int d = 0; d < 16; ++d) o[d] += e * vv[d];
      }
#pragma unroll
      for (int d = 0; d < 16; ++d) o[d] += __shfl_xor(o[d], 1);
      se += __shfl_xor(se, 1);
#pragma unroll
      for (int d = 0; d < 16; ++d) o[d] += __shfl_xor(o[d], 2);
      se += __shfl_xor(se, 2);
      if (sub == 0) {
        const float inv = 1.f / se;
        uint4 w0, w1;
        w0.x = (unsigned)f2bf(o[0] * inv)  | ((unsigned)f2bf(o[1] * inv) << 16);
        w0.y = (unsigned)f2bf(o[2] * inv)  | ((unsigned)f2bf(o[3] * inv) << 16);
        w0.z = (unsigned)f2bf(o[4] * inv)  | ((unsigned)f2bf(o[5] * inv) << 16);
        w0.w = (unsigned)f2bf(o[6] * inv)  | ((unsigned)f2bf(o[7] * inv) << 16);
        w1.x = (unsigned)f2bf(o[8] * inv)  | ((unsigned)f2bf(o[9] * inv) << 16);
        w1.y = (unsigned)f2bf(o[10] * inv) | ((unsigned)f2bf(o[11] * inv) << 16);
        w1.z = (unsigned)f2bf(o[12] * inv) | ((unsigned)f2bf(o[13] * inv) << 16);
        w1.w = (unsigned)f2bf(o[14] * inv) | ((unsigned)f2bf(o[15] * inv) << 16);
        *(uint4*)&sm.g.A16[pr >> 3][h * 16]     = w0;
        *(uint4*)&sm.g.A16[pr >> 3][h * 16 + 8] = w1;
      }
    }
    __syncthreads();
    // --- ao GEMM + residual: X += O @ ao_w.T + b ---
    {
      const u16* Bw = p.W + OFF_AO + l * 16384;
      const float* ab = p.ao_b + l * 128;
      const int col = w * 16 + lr;
      floatx4 acc = FZ;
#pragma unroll
      for (int k0 = 0; k0 < 128; k0 += 32) {
        short8_t a = *(const short8_t*)&sm.g.A16[lr][k0 + quad * 8];
        short8_t b = *(const short8_t*)&Bw[(size_t)col * 128 + k0 + quad * 8];
        acc = __builtin_amdgcn_mfma_f32_16x16x32_bf16(a, b, acc, 0, 0, 0);
      }
      const float bv = ab[col];
#pragma unroll
      for (int r = 0; r < 4; ++r)
        p.X[(size_t)(r0 + quad * 4 + r) * H + col] += acc[r] + bv;
    }
    __syncthreads();
    // --- LN2 -> f1 (relu) -> FF1 in LDS ---
    stage_x(p.ln2_s + l * 128, p.ln2_b + l * 128, true);
    __syncthreads();
    {
      const u16* Bw = p.W + OFF_F1 + l * 32768;
      const float* fb = p.f1_b + l * 256;
      const int c0 = w * 32;
      floatx4 a0 = FZ, a1 = FZ;
#pragma unroll
      for (int k0 = 0; k0 < 128; k0 += 32) {
        short8_t a  = *(const short8_t*)&sm.g.A16[lr][k0 + quad * 8];
        short8_t b0 = *(const short8_t*)&Bw[(size_t)(c0 + lr) * 128 + k0 + quad * 8];
        short8_t b1 = *(const short8_t*)&Bw[(size_t)(c0 + 16 + lr) * 128 + k0 + quad * 8];
        a0 = __builtin_amdgcn_mfma_f32_16x16x32_bf16(a, b0, a0, 0, 0, 0);
        a1 = __builtin_amdgcn_mfma_f32_16x16x32_bf16(a, b1, a1, 0, 0, 0);
      }
#pragma unroll
      for (int r = 0; r < 4; ++r) {
        const int row = quad * 4 + r;
        sm.g.FF1[row][c0 + lr]      = f2bf(fmaxf(a0[r] + fb[c0 + lr], 0.f));
        sm.g.FF1[row][c0 + 16 + lr] = f2bf(fmaxf(a1[r] + fb[c0 + 16 + lr], 0.f));
      }
    }
    __syncthreads();
    // --- f2 + residual: X += relu(.) @ f2_w.T + b ---
    {
      const u16* Bw = p.W + OFF_F2 + l * 32768;
      const float* fb = p.f2_b + l * 128;
      const int col = w * 16 + lr;
      floatx4 acc = FZ;
#pragma unroll
      for (int k0 = 0; k0 < 256; k0 += 32) {
        short8_t a = *(const short8_t*)&sm.g.FF1[lr][k0 + quad * 8];
        short8_t b = *(const short8_t*)&Bw[(size_t)col * 256 + k0 + quad * 8];
        acc = __builtin_amdgcn_mfma_f32_16x16x32_bf16(a, b, acc, 0, 0, 0);
      }
      const float bv = fb[col];
#pragma unroll
      for (int r = 0; r < 4; ++r)
        p.X[(size_t)(r0 + quad * 4 + r) * H + col] += acc[r] + bv;
    }
    __syncthreads();
    if (l < 3) {
      // --- LN1 -> qkv for next layer (row-local, no grid sync needed) ---
      stage_x(p.ln1_s + (l + 1) * 128, p.ln1_b + (l + 1) * 128, true);
      __syncthreads();
      qkv_phase(l + 1);
      grid.sync();    // qkv of ALL rows must land before next attn
    } else {
      // --- heads: [lat1|b1] GEMM (N=192) -> lat2+normalize, beta ---
      stage_x(nullptr, nullptr, false);
      __syncthreads();
      {
        const int c0 = w * 32;
        if (c0 < 192) {
          const u16* Bw = p.W + OFF_LAT1;
          floatx4 a0 = FZ, a1 = FZ;
#pragma unroll
          for (int k0 = 0; k0 < 128; k0 += 32) {
            short8_t a  = *(const short8_t*)&sm.g.A16[lr][k0 + quad * 8];
            short8_t b0 = *(const short8_t*)&Bw[(size_t)(c0 + lr) * 128 + k0 + quad * 8];
            short8_t b1 = *(const short8_t*)&Bw[(size_t)(c0 + 16 + lr) * 128 + k0 + quad * 8];
            a0 = __builtin_amdgcn_mfma_f32_16x16x32_bf16(a, b0, a0, 0, 0, 0);
            a1 = __builtin_amdgcn_mfma_f32_16x16x32_bf16(a, b1, a1, 0, 0, 0);
          }
          const int cA = c0 + lr, cB = c0 + 16 + lr;
          const float bA = cA < 128 ? p.lat1_b[cA] : p.b1_b[cA - 128];
          const float bB = cB < 128 ? p.lat1_b[cB] : p.b1_b[cB - 128];
#pragma unroll
          for (int r = 0; r < 4; ++r) {
            const int row = quad * 4 + r;
            sm.g.FF1[row][cA] = f2bf(fmaxf(a0[r] + bA, 0.f));
            sm.g.FF1[row][cB] = f2bf(fmaxf(a1[r] + bB, 0.f));
          }
        }
      }
      __syncthreads();
      if (t < 256) {
        const int r = t >> 4, c = t & 15;
        float acc = p.lat2_b[c];
        const u16* gw = p.W + OFF_LAT2 + c * 128;
        for (int k = 0; k < 128; ++k) acc += bfu(sm.g.FF1[r][k]) * bfu(gw[k]);
        float ss = acc * acc;
        ss += __shfl_xor(ss, 1); ss += __shfl_xor(ss, 2);
        ss += __shfl_xor(ss, 4); ss += __shfl_xor(ss, 8);
        p.out[NT + (size_t)(r0 + r) * 16 + c] = acc / fmaxf(sqrtf(ss), 1e-12f);
        float v = 0.f;
#pragma unroll
        for (int i = 0; i < 4; ++i)
          v += bfu(sm.g.FF1[r][128 + c * 4 + i]) * p.b2_w[c * 4 + i];
        v += __shfl_xor(v, 1); v += __shfl_xor(v, 2);
        v += __shfl_xor(v, 4); v += __shfl_xor(v, 8);
        if (c == 0) {
          v += p.b2_b[0];
          const float beta = 1.f / (1.f + expf(-v));
          p.out[r0 + r] = fminf(fmaxf(beta, 1e-6f), 1.f - 1e-6f);
        }
      }
    }
  }
}

extern "C" void kernel_launch(void* const* d_in, const int* in_sizes, int n_in,
                              void* d_out, int out_size, void* d_ws, size_t ws_size,
                              hipStream_t stream) {
  Prm prm;
  prm.xr    = (const float*)d_in[0];
  prm.in_w  = (const float*)d_in[2];  prm.in_b  = (const float*)d_in[3];
  prm.ln1_s = (const float*)d_in[4];  prm.ln1_b = (const float*)d_in[5];
  prm.qkv_w = (const float*)d_in[6];  prm.qkv_b = (const float*)d_in[7];
  prm.ao_w  = (const float*)d_in[8];  prm.ao_b  = (const float*)d_in[9];
  prm.ln2_s = (const float*)d_in[10]; prm.ln2_b = (const float*)d_in[11];
  prm.f1_w  = (const float*)d_in[12]; prm.f1_b  = (const float*)d_in[13];
  prm.f2_w  = (const float*)d_in[14]; prm.f2_b  = (const float*)d_in[15];
  prm.lat1_w= (const float*)d_in[16]; prm.lat1_b= (const float*)d_in[17];
  prm.lat2_w= (const float*)d_in[18]; prm.lat2_b= (const float*)d_in[19];
  prm.b1_w  = (const float*)d_in[20]; prm.b1_b  = (const float*)d_in[21];
  prm.b2_w  = (const float*)d_in[22]; prm.b2_b  = (const float*)d_in[23];
  prm.out   = (float*)d_out;

  char* pw = (char*)d_ws;
  prm.W   = (u16*)pw;    pw += ((size_t)W_TOTAL * 2 + 255) & ~(size_t)255;
  prm.X   = (float*)pw;  pw += (size_t)NT * H * 4;
  prm.QKV = (u16*)pw;    pw += (size_t)NT * 384 * 2;
  prm.NI  = (int*)pw;    pw += (size_t)NT * CAP * 4;
  prm.NC  = (int*)pw;    pw += (size_t)NT * 4;
  prm.EP  = (double*)pw; pw += (size_t)NT * 16;

  void* args[] = {&prm};
  hipLaunchCooperativeKernel((const void*)mega_kernel, dim3(GRID), dim3(BLK),
                             args, 0, stream);
}

// Round 4
// 248.310 us; speedup vs baseline: 1.5231x; 1.5231x over previous
//
#include <hip/hip_runtime.h>
#include <hip/hip_bf16.h>

typedef unsigned short u16;
typedef short short8_t __attribute__((ext_vector_type(8)));
typedef float floatx4 __attribute__((ext_vector_type(4)));

constexpr int NT = 4096, H = 128, CAP = 64;
constexpr int GRID = 256, BLK = 512, GSTRIDE = GRID * BLK;

// bf16 weight arena element offsets (lat1+b1 contiguous -> one 192-col head GEMM)
constexpr int OFF_QKV  = 0;                 // 4*384*128
constexpr int OFF_AO   = 196608;            // 4*128*128
constexpr int OFF_F1   = 262144;            // 4*256*128
constexpr int OFF_F2   = 393216;            // 4*128*256
constexpr int OFF_LAT1 = 524288;            // 128*128
constexpr int OFF_B1   = 540672;            // 64*128
constexpr int OFF_LAT2 = 548864;            // 16*128
constexpr int W_TOTAL  = 550912;

__device__ __forceinline__ float bfu(u16 u) { return __uint_as_float(((unsigned)u) << 16); }
__device__ __forceinline__ u16 f2bf(float f) {
  unsigned u = __float_as_uint(f);
  u += 0x7fffu + ((u >> 16) & 1u);          // RNE
  return (u16)(u >> 16);
}
__device__ __forceinline__ void unpack8(uint4 u, float* f) {
  f[0] = __uint_as_float(u.x << 16); f[1] = __uint_as_float(u.x & 0xffff0000u);
  f[2] = __uint_as_float(u.y << 16); f[3] = __uint_as_float(u.y & 0xffff0000u);
  f[4] = __uint_as_float(u.z << 16); f[5] = __uint_as_float(u.z & 0xffff0000u);
  f[6] = __uint_as_float(u.w << 16); f[7] = __uint_as_float(u.w & 0xffff0000u);
}

struct Prm {
  const float *xr, *in_w, *in_b, *ln1_s, *ln1_b, *qkv_w, *qkv_b, *ao_w, *ao_b,
              *ln2_s, *ln2_b, *f1_w, *f1_b, *f2_w, *f2_b, *lat1_w, *lat1_b,
              *lat2_w, *lat2_b, *b1_w, *b1_b, *b2_w, *b2_b;
  u16* W; u16* QKV0; u16* QKV1; double* EP; unsigned* Barr; float* out;
};

// Lightweight grid barrier: Barr[0]=arrive, Barr[64]=release, Barr[128]=init.
// ws is poisoned 0xAA each launch -> init handshake before first use.
__device__ __forceinline__ void gbar(unsigned* B, unsigned phase, int t) {
  __syncthreads();
  if (t == 0) {
    __threadfence();                         // agent release (L2 wb)
    const unsigned tk =
        __hip_atomic_fetch_add(B, 1u, __ATOMIC_RELAXED, __HIP_MEMORY_SCOPE_AGENT);
    if (tk == (unsigned)GRID * phase - 1) {
      __hip_atomic_store(B + 64, phase, __ATOMIC_RELAXED, __HIP_MEMORY_SCOPE_AGENT);
    } else {
      unsigned v;
      do {
        __builtin_amdgcn_s_sleep(1);
        v = __hip_atomic_load(B + 64, __ATOMIC_RELAXED, __HIP_MEMORY_SCOPE_AGENT);
      } while (v < phase);
    }
    __threadfence();                         // agent acquire (L1/L2 inv)
  }
  __syncthreads();
}

// One persistent kernel: block b owns token rows [16b,16b+16) end-to-end.
// X, neighbor lists, FF intermediates live in LDS; only W/EP/QKV cross blocks.
__global__ __launch_bounds__(BLK, 4) void mega_kernel(Prm p) {
  const int t = threadIdx.x, bid = blockIdx.x;
  const int lane = t & 63, w = t >> 6;          // 8 waves
  const int lr = lane & 15, quad = lane >> 4;
  const int gtid = bid * BLK + t;
  const int r0 = bid * 16;                      // this block's 16 token rows
  const floatx4 FZ = {0.f, 0.f, 0.f, 0.f};

  __shared__ float Xs[16][132];                 // residual master, block-local
  __shared__ int NIs[16][CAP];                  // neighbor lists, block-local
  __shared__ int NCs[16];
  __shared__ union {
    unsigned long long words[8][64];                     // 4 KB (nbr stage)
    struct { u16 A16[16][136]; u16 FF1[16][264]; } g;    // 12.8 KB
  } sm;

  // ---- barrier init (block 0 publishes zeroed counters + magic flag) ----
  if (bid == 0 && t == 0) {
    __hip_atomic_store(p.Barr,      0u, __ATOMIC_RELAXED, __HIP_MEMORY_SCOPE_AGENT);
    __hip_atomic_store(p.Barr + 64, 0u, __ATOMIC_RELAXED, __HIP_MEMORY_SCOPE_AGENT);
    __threadfence();
    __hip_atomic_store(p.Barr + 128, 0xC0FFEEu, __ATOMIC_RELAXED, __HIP_MEMORY_SCOPE_AGENT);
  }

  auto stage_x = [&](const float* sc, const float* bi, bool do_ln) {
    const int r = t >> 5, j0 = (t & 31) * 4;    // 32 lanes per row
    const float4 xv = *(const float4*)&Xs[r][j0];
    float v0 = xv.x, v1 = xv.y, v2 = xv.z, v3 = xv.w;
    if (do_ln) {
      float s = v0 + v1 + v2 + v3;
      float ss = v0 * v0 + v1 * v1 + v2 * v2 + v3 * v3;
#pragma unroll
      for (int off = 1; off <= 16; off <<= 1) {
        s += __shfl_xor(s, off); ss += __shfl_xor(ss, off);
      }
      const float mean = s * (1.f / 128.f);
      const float rstd = rsqrtf(ss * (1.f / 128.f) - mean * mean + 1e-5f);
      v0 = (v0 - mean) * rstd * sc[j0]     + bi[j0];
      v1 = (v1 - mean) * rstd * sc[j0 + 1] + bi[j0 + 1];
      v2 = (v2 - mean) * rstd * sc[j0 + 2] + bi[j0 + 2];
      v3 = (v3 - mean) * rstd * sc[j0 + 3] + bi[j0 + 3];
    }
    uint2 pk;
    pk.x = (unsigned)f2bf(v0) | ((unsigned)f2bf(v1) << 16);
    pk.y = (unsigned)f2bf(v2) | ((unsigned)f2bf(v3) << 16);
    *(uint2*)&sm.g.A16[r][j0] = pk;
  };

  auto qkv_phase = [&](int lw, u16* dst) {
    const u16* Bw = p.W + OFF_QKV + lw * 49152;
    const float* qb = p.qkv_b + lw * 384;
    const int c0 = w * 48;
    floatx4 a0 = FZ, a1 = FZ, a2 = FZ;
#pragma unroll
    for (int k0 = 0; k0 < 128; k0 += 32) {
      short8_t a  = *(const short8_t*)&sm.g.A16[lr][k0 + quad * 8];
      short8_t b0 = *(const short8_t*)&Bw[(size_t)(c0 + lr) * 128 + k0 + quad * 8];
      short8_t b1 = *(const short8_t*)&Bw[(size_t)(c0 + 16 + lr) * 128 + k0 + quad * 8];
      short8_t b2 = *(const short8_t*)&Bw[(size_t)(c0 + 32 + lr) * 128 + k0 + quad * 8];
      a0 = __builtin_amdgcn_mfma_f32_16x16x32_bf16(a, b0, a0, 0, 0, 0);
      a1 = __builtin_amdgcn_mfma_f32_16x16x32_bf16(a, b1, a1, 0, 0, 0);
      a2 = __builtin_amdgcn_mfma_f32_16x16x32_bf16(a, b2, a2, 0, 0, 0);
    }
#pragma unroll
    for (int r = 0; r < 4; ++r) {
      const size_t row = (size_t)(r0 + quad * 4 + r) * 384;
      dst[row + c0 + lr]      = f2bf(a0[r] + qb[c0 + lr]);
      dst[row + c0 + 16 + lr] = f2bf(a1[r] + qb[c0 + 16 + lr]);
      dst[row + c0 + 32 + lr] = f2bf(a2[r] + qb[c0 + 32 + lr]);
    }
  };

  // ================= stage P: wconv + eta/phi + in_proj(LDS) =================
  for (int i = gtid; i < W_TOTAL; i += GSTRIDE) {
    float v;
    if      (i < OFF_AO)   v = p.qkv_w[i];
    else if (i < OFF_F1)   v = p.ao_w[i - OFF_AO];
    else if (i < OFF_F2)   v = p.f1_w[i - OFF_F1];
    else if (i < OFF_LAT1) v = p.f2_w[i - OFF_F2];
    else if (i < OFF_B1)   v = p.lat1_w[i - OFF_LAT1];
    else if (i < OFF_LAT2) v = p.b1_w[i - OFF_B1];
    else                   v = p.lat2_w[i - OFF_LAT2];
    p.W[i] = f2bf(v);
  }
  if (gtid < NT) {
    p.EP[gtid * 2]     = (double)p.xr[gtid * 16 + 1] * 5.24 - 2.62;
    p.EP[gtid * 2 + 1] = (double)p.xr[gtid * 16 + 2] * 6.2832 - 3.1416;
  }
  for (int i = t; i < 16 * H; i += BLK) {       // in_proj for own 16 rows
    const int r = i >> 7, c = i & 127;
    const float* xp = p.xr + (size_t)(r0 + r) * 16;
    const float* wp = p.in_w + c * 16;
    float acc = p.in_b[c];
#pragma unroll
    for (int k = 0; k < 16; ++k) acc += xp[k] * wp[k];
    Xs[r][c] = acc;
  }
  // wait for barrier init, then global sync (W, EP visible)
  if (t == 0) {
    unsigned v;
    do {
      __builtin_amdgcn_s_sleep(1);
      v = __hip_atomic_load(p.Barr + 128, __ATOMIC_RELAXED, __HIP_MEMORY_SCOPE_AGENT);
    } while (v != 0xC0FFEEu);
  }
  gbar(p.Barr, 1, t);

  // ============ stage N: own-row neighbor lists (LDS) + qkv layer 0 ============
  for (int uu = 0; uu < 2; ++uu) {
    const int q0 = r0 + uu * 8;
    double qe[8], qp_[8];
#pragma unroll
    for (int j = 0; j < 8; ++j) { qe[j] = p.EP[(q0 + j) * 2]; qp_[j] = p.EP[(q0 + j) * 2 + 1]; }
    for (int c = 0; c < 8; ++c) {
      const int k = c * 512 + t;
      const double ke = p.EP[k * 2], kp = p.EP[k * 2 + 1];
#pragma unroll
      for (int j = 0; j < 8; ++j) {
        const double de = qe[j] - ke;
        double dp = qp_[j] - kp;
        dp -= 6.283185307179586 * rint(dp * 0.15915494309189535);  // atan2 wrap
        const unsigned long long bm = __ballot((de * de + dp * dp) <= 0.04);
        if (lane == 0) sm.words[j][c * 8 + w] = bm;
      }
    }
    __syncthreads();
    {
      unsigned long long m = sm.words[w][lane];
      const int cnt = __popcll(m);
      int incl = cnt;
#pragma unroll
      for (int off = 1; off < 64; off <<= 1) {
        const int n = __shfl_up(incl, off);
        if (lane >= off) incl += n;
      }
      int pos = incl - cnt;
      const int lq = uu * 8 + w;
      const int kbase = (lane >> 3) * 512 + (lane & 7) * 64;
      while (m) {
        const int b = __builtin_ctzll(m);
        m &= m - 1;
        if (pos < CAP) NIs[lq][pos] = kbase + b;
        ++pos;
      }
      if (lane == 63) NCs[lq] = incl > CAP ? CAP : incl;
    }
    __syncthreads();
  }
  stage_x(p.ln1_s, p.ln1_b, true);
  __syncthreads();
  qkv_phase(0, p.QKV0);
  gbar(p.Barr, 2, t);

  // ================= layer stages =================
  for (int l = 0; l < 4; ++l) {
    const u16* qbuf = (l & 1) ? p.QKV1 : p.QKV0;
    // --- attention: 128 (q,h) pairs, 4 threads/pair over neighbors ---
    {
      const int pr = t >> 2, sub = t & 3;
      const int lq = pr >> 3, h = pr & 7;
      const u16* qp = qbuf + (size_t)(r0 + lq) * 384 + h * 16;
      float qv[16];
      { uint4 a = *(const uint4*)qp, b = *(const uint4*)(qp + 8);
        unpack8(a, qv); unpack8(b, qv + 8); }
#pragma unroll
      for (int d = 0; d < 16; ++d) qv[d] *= 0.25f;      // 1/sqrt(HD)
      float o[16];
#pragma unroll
      for (int d = 0; d < 16; ++d) o[d] = 0.f;
      float se = 0.f;
      const int cnt = NCs[lq];
      for (int i = sub; i < cnt; i += 4) {
        const int nb = NIs[lq][i];
        const u16* kp = qbuf + (size_t)nb * 384 + 128 + h * 16;
        float kv[16], vv[16];
        { uint4 a = *(const uint4*)kp;         uint4 b = *(const uint4*)(kp + 8);
          unpack8(a, kv); unpack8(b, kv + 8); }
        { uint4 a = *(const uint4*)(kp + 128); uint4 b = *(const uint4*)(kp + 136);
          unpack8(a, vv); unpack8(b, vv + 8); }
        float s0 = 0.f, s1 = 0.f, s2 = 0.f, s3 = 0.f;
#pragma unroll
        for (int d = 0; d < 16; d += 4) {
          s0 += qv[d] * kv[d];         s1 += qv[d + 1] * kv[d + 1];
          s2 += qv[d + 2] * kv[d + 2]; s3 += qv[d + 3] * kv[d + 3];
        }
        const float e = expf((s0 + s1) + (s2 + s3));    // |s|<~0.5, no max-sub
        se += e;
#pragma unroll
        for (int d = 0; d < 16; ++d) o[d] += e * vv[d];
      }
#pragma unroll
      for (int d = 0; d < 16; ++d) o[d] += __shfl_xor(o[d], 1);
      se += __shfl_xor(se, 1);
#pragma unroll
      for (int d = 0; d < 16; ++d) o[d] += __shfl_xor(o[d], 2);
      se += __shfl_xor(se, 2);
      if (sub == 0) {
        const float inv = 1.f / se;
        uint4 w0, w1;
        w0.x = (unsigned)f2bf(o[0] * inv)  | ((unsigned)f2bf(o[1] * inv) << 16);
        w0.y = (unsigned)f2bf(o[2] * inv)  | ((unsigned)f2bf(o[3] * inv) << 16);
        w0.z = (unsigned)f2bf(o[4] * inv)  | ((unsigned)f2bf(o[5] * inv) << 16);
        w0.w = (unsigned)f2bf(o[6] * inv)  | ((unsigned)f2bf(o[7] * inv) << 16);
        w1.x = (unsigned)f2bf(o[8] * inv)  | ((unsigned)f2bf(o[9] * inv) << 16);
        w1.y = (unsigned)f2bf(o[10] * inv) | ((unsigned)f2bf(o[11] * inv) << 16);
        w1.z = (unsigned)f2bf(o[12] * inv) | ((unsigned)f2bf(o[13] * inv) << 16);
        w1.w = (unsigned)f2bf(o[14] * inv) | ((unsigned)f2bf(o[15] * inv) << 16);
        *(uint4*)&sm.g.A16[lq][h * 16]     = w0;
        *(uint4*)&sm.g.A16[lq][h * 16 + 8] = w1;
      }
    }
    __syncthreads();
    // --- ao GEMM + residual (LDS X) ---
    {
      const u16* Bw = p.W + OFF_AO + l * 16384;
      const float* ab = p.ao_b + l * 128;
      const int col = w * 16 + lr;
      floatx4 acc = FZ;
#pragma unroll
      for (int k0 = 0; k0 < 128; k0 += 32) {
        short8_t a = *(const short8_t*)&sm.g.A16[lr][k0 + quad * 8];
        short8_t b = *(const short8_t*)&Bw[(size_t)col * 128 + k0 + quad * 8];
        acc = __builtin_amdgcn_mfma_f32_16x16x32_bf16(a, b, acc, 0, 0, 0);
      }
      const float bv = ab[col];
#pragma unroll
      for (int r = 0; r < 4; ++r)
        Xs[quad * 4 + r][col] += acc[r] + bv;
    }
    __syncthreads();
    // --- LN2 -> f1 (relu) -> FF1 in LDS ---
    stage_x(p.ln2_s + l * 128, p.ln2_b + l * 128, true);
    __syncthreads();
    {
      const u16* Bw = p.W + OFF_F1 + l * 32768;
      const float* fb = p.f1_b + l * 256;
      const int c0 = w * 32;
      floatx4 a0 = FZ, a1 = FZ;
#pragma unroll
      for (int k0 = 0; k0 < 128; k0 += 32) {
        short8_t a  = *(const short8_t*)&sm.g.A16[lr][k0 + quad * 8];
        short8_t b0 = *(const short8_t*)&Bw[(size_t)(c0 + lr) * 128 + k0 + quad * 8];
        short8_t b1 = *(const short8_t*)&Bw[(size_t)(c0 + 16 + lr) * 128 + k0 + quad * 8];
        a0 = __builtin_amdgcn_mfma_f32_16x16x32_bf16(a, b0, a0, 0, 0, 0);
        a1 = __builtin_amdgcn_mfma_f32_16x16x32_bf16(a, b1, a1, 0, 0, 0);
      }
#pragma unroll
      for (int r = 0; r < 4; ++r) {
        const int row = quad * 4 + r;
        sm.g.FF1[row][c0 + lr]      = f2bf(fmaxf(a0[r] + fb[c0 + lr], 0.f));
        sm.g.FF1[row][c0 + 16 + lr] = f2bf(fmaxf(a1[r] + fb[c0 + 16 + lr], 0.f));
      }
    }
    __syncthreads();
    // --- f2 + residual (LDS X) ---
    {
      const u16* Bw = p.W + OFF_F2 + l * 32768;
      const float* fb = p.f2_b + l * 128;
      const int col = w * 16 + lr;
      floatx4 acc = FZ;
#pragma unroll
      for (int k0 = 0; k0 < 256; k0 += 32) {
        short8_t a = *(const short8_t*)&sm.g.FF1[lr][k0 + quad * 8];
        short8_t b = *(const short8_t*)&Bw[(size_t)col * 256 + k0 + quad * 8];
        acc = __builtin_amdgcn_mfma_f32_16x16x32_bf16(a, b, acc, 0, 0, 0);
      }
      const float bv = fb[col];
#pragma unroll
      for (int r = 0; r < 4; ++r)
        Xs[quad * 4 + r][col] += acc[r] + bv;
    }
    __syncthreads();
    if (l < 3) {
      stage_x(p.ln1_s + (l + 1) * 128, p.ln1_b + (l + 1) * 128, true);
      __syncthreads();
      qkv_phase(l + 1, (l & 1) ? p.QKV0 : p.QKV1);   // write the OTHER buffer
      gbar(p.Barr, 3 + l, t);                        // qkv of all rows visible
    } else {
      // --- heads: [lat1|b1] (N=192) -> lat2+normalize, beta ---
      stage_x(nullptr, nullptr, false);
      __syncthreads();
      {
        const int c0 = w * 32;
        if (c0 < 192) {
          const u16* Bw = p.W + OFF_LAT1;
          floatx4 a0 = FZ, a1 = FZ;
#pragma unroll
          for (int k0 = 0; k0 < 128; k0 += 32) {
            short8_t a  = *(const short8_t*)&sm.g.A16[lr][k0 + quad * 8];
            short8_t b0 = *(const short8_t*)&Bw[(size_t)(c0 + lr) * 128 + k0 + quad * 8];
            short8_t b1 = *(const short8_t*)&Bw[(size_t)(c0 + 16 + lr) * 128 + k0 + quad * 8];
            a0 = __builtin_amdgcn_mfma_f32_16x16x32_bf16(a, b0, a0, 0, 0, 0);
            a1 = __builtin_amdgcn_mfma_f32_16x16x32_bf16(a, b1, a1, 0, 0, 0);
          }
          const int cA = c0 + lr, cB = c0 + 16 + lr;
          const float bA = cA < 128 ? p.lat1_b[cA] : p.b1_b[cA - 128];
          const float bB = cB < 128 ? p.lat1_b[cB] : p.b1_b[cB - 128];
#pragma unroll
          for (int r = 0; r < 4; ++r) {
            const int row = quad * 4 + r;
            sm.g.FF1[row][cA] = f2bf(fmaxf(a0[r] + bA, 0.f));
            sm.g.FF1[row][cB] = f2bf(fmaxf(a1[r] + bB, 0.f));
          }
        }
      }
      __syncthreads();
      if (t < 256) {
        const int r = t >> 4, c = t & 15;
        float acc = p.lat2_b[c];
        const u16* gw = p.W + OFF_LAT2 + c * 128;
        for (int k = 0; k < 128; ++k) acc += bfu(sm.g.FF1[r][k]) * bfu(gw[k]);
        float ss = acc * acc;
        ss += __shfl_xor(ss, 1); ss += __shfl_xor(ss, 2);
        ss += __shfl_xor(ss, 4); ss += __shfl_xor(ss, 8);
        p.out[NT + (size_t)(r0 + r) * 16 + c] = acc / fmaxf(sqrtf(ss), 1e-12f);
        float v = 0.f;
#pragma unroll
        for (int i = 0; i < 4; ++i)
          v += bfu(sm.g.FF1[r][128 + c * 4 + i]) * p.b2_w[c * 4 + i];
        v += __shfl_xor(v, 1); v += __shfl_xor(v, 2);
        v += __shfl_xor(v, 4); v += __shfl_xor(v, 8);
        if (c == 0) {
          v += p.b2_b[0];
          const float beta = 1.f / (1.f + expf(-v));
          p.out[r0 + r] = fminf(fmaxf(beta, 1e-6f), 1.f - 1e-6f);
        }
      }
    }
  }
}

extern "C" void kernel_launch(void* const* d_in, const int* in_sizes, int n_in,
                              void* d_out, int out_size, void* d_ws, size_t ws_size,
                              hipStream_t stream) {
  Prm prm;
  prm.xr    = (const float*)d_in[0];
  prm.in_w  = (const float*)d_in[2];  prm.in_b  = (const float*)d_in[3];
  prm.ln1_s = (const float*)d_in[4];  prm.ln1_b = (const float*)d_in[5];
  prm.qkv_w = (const float*)d_in[6];  prm.qkv_b = (const float*)d_in[7];
  prm.ao_w  = (const float*)d_in[8];  prm.ao_b  = (const float*)d_in[9];
  prm.ln2_s = (const float*)d_in[10]; prm.ln2_b = (const float*)d_in[11];
  prm.f1_w  = (const float*)d_in[12]; prm.f1_b  = (const float*)d_in[13];
  prm.f2_w  = (const float*)d_in[14]; prm.f2_b  = (const float*)d_in[15];
  prm.lat1_w= (const float*)d_in[16]; prm.lat1_b= (const float*)d_in[17];
  prm.lat2_w= (const float*)d_in[18]; prm.lat2_b= (const float*)d_in[19];
  prm.b1_w  = (const float*)d_in[20]; prm.b1_b  = (const float*)d_in[21];
  prm.b2_w  = (const float*)d_in[22]; prm.b2_b  = (const float*)d_in[23];
  prm.out   = (float*)d_out;

  char* pw = (char*)d_ws;
  prm.Barr = (unsigned*)pw; pw += 1024;
  prm.W    = (u16*)pw;      pw += ((size_t)W_TOTAL * 2 + 255) & ~(size_t)255;
  prm.QKV0 = (u16*)pw;      pw += (size_t)NT * 384 * 2;
  prm.QKV1 = (u16*)pw;      pw += (size_t)NT * 384 * 2;
  prm.EP   = (double*)pw;   pw += (size_t)NT * 16;

  Prm* arg = &prm;
  hipLaunchKernelGGL(mega_kernel, dim3(GRID), dim3(BLK), 0, stream, *arg);
}